// Round 12
// baseline (123.672 us; speedup 1.0000x reference)
//
#include <hip/hip_runtime.h>

#define POISON 0xAAAAAAAAu
#define NMLP 16u

// Exact (non-approximate) GELU, matching jax.nn.gelu(approximate=False).
__device__ __forceinline__ float gelu_exact(float x) {
    return 0.5f * x * (1.0f + erff(x * 0.7071067811865475f));
}

__device__ __forceinline__ float dot4(float4 a, float4 b) {
    return a.x * b.x + a.y * b.y + a.z * b.z + a.w * b.w;
}

// Barrier among the NMLP=16 MLP blocks. Slot starts as harness poison; every
// participant CASes POISON->0 BEFORE spinning, so no participant can ever
// observe POISON in its spin (first CAS system-wide zeroes the slot).
// 16-way RMW arrival is ~16x cheaper than r9's 256-way (its ~20us/barrier).
__device__ __forceinline__ void mlp_barrier(unsigned* slot) {
    __syncthreads();
    if (threadIdx.x == 0) {
        atomicCAS(slot, POISON, 0u);
        __threadfence();
        atomicAdd(slot, 1u);
        while (__hip_atomic_load(slot, __ATOMIC_ACQUIRE,
                                 __HIP_MEMORY_SCOPE_AGENT) < NMLP)
            __builtin_amdgcn_s_sleep(2);
    }
    __syncthreads();
}

// ONE dispatch, 256 blocks x 256 threads.
//  blocks 0..15 : cooperative MLP. Block m owns neurons m*16..m*16+15 of each
//                 256x256 layer (16 thr/neuron, coalesced 256B club reads,
//                 4-step shfl reduce). x handoff via agent-scope ws buffers;
//                 two 16-block barriers (x2, x3). L5 = per-block partials
//                 merged with 12 fp32 atomicAdds + a 16-arrival done counter.
//  all blocks   : spin read-only until done==16 (load-only, 512cy backoff),
//                 then apply their 1/256 slice: pred = feat . w12.
__global__ __launch_bounds__(256) void fused3_kernel(
    const float* __restrict__ W1, const float* __restrict__ b1,
    const float* __restrict__ W2, const float* __restrict__ b2,
    const float* __restrict__ W3, const float* __restrict__ b3,
    const float* __restrict__ W4, const float* __restrict__ b4,
    const float* __restrict__ W5, const float* __restrict__ b5,
    const float* __restrict__ feat, float* __restrict__ out,
    float* __restrict__ ws)
{
    float*    w12  = ws;                          // 12 float accumulators
    unsigned* barA = (unsigned*)(ws + 32);
    unsigned* barB = (unsigned*)(ws + 64);
    unsigned* done = (unsigned*)(ws + 96);
    float*    xb2  = ws + 128;                    // 256 floats
    float*    xb3  = ws + 384;                    // 256 floats

    __shared__ __align__(16) float xs[256];
    __shared__ float x4loc[16];
    __shared__ float wl[12];

    const int t = threadIdx.x;
    const int m = blockIdx.x;

    if (m < (int)NMLP) {
        const int q = t >> 4;          // neuron-in-block 0..15
        const int c = t & 15;          // k-club lane 0..15
        const int n = m * 16 + q;      // global neuron id

        // ---- Layer 1 (redundant per MLP block; W1 is 4KB) ----
        {
            float4 w1r = *reinterpret_cast<const float4*>(W1 + t * 4);
            xs[t] = gelu_exact(w1r.z + w1r.w + b1[t]);
        }
        __syncthreads();

        // ---- Layer 2: club reads 4x256B contiguous segments of row n ----
        {
            float acc = 0.f;
            #pragma unroll
            for (int i = 0; i < 4; ++i) {
                float4 wv = *reinterpret_cast<const float4*>(W2 + (size_t)n * 256 + i * 64 + c * 4);
                float4 xv = *reinterpret_cast<const float4*>(xs + i * 64 + c * 4);
                acc += dot4(wv, xv);
            }
            #pragma unroll
            for (int off = 1; off <= 8; off <<= 1) acc += __shfl_xor(acc, off);
            if (c == 0)
                __hip_atomic_store(&xb2[n], gelu_exact(acc + b2[n]),
                                   __ATOMIC_RELEASE, __HIP_MEMORY_SCOPE_AGENT);
        }
        mlp_barrier(barA);

        // ---- Layer 3 ----
        xs[t] = __hip_atomic_load(&xb2[t], __ATOMIC_ACQUIRE, __HIP_MEMORY_SCOPE_AGENT);
        __syncthreads();
        {
            float acc = 0.f;
            #pragma unroll
            for (int i = 0; i < 4; ++i) {
                float4 wv = *reinterpret_cast<const float4*>(W3 + (size_t)n * 256 + i * 64 + c * 4);
                float4 xv = *reinterpret_cast<const float4*>(xs + i * 64 + c * 4);
                acc += dot4(wv, xv);
            }
            #pragma unroll
            for (int off = 1; off <= 8; off <<= 1) acc += __shfl_xor(acc, off);
            if (c == 0)
                __hip_atomic_store(&xb3[n], gelu_exact(acc + b3[n]),
                                   __ATOMIC_RELEASE, __HIP_MEMORY_SCOPE_AGENT);
        }
        mlp_barrier(barB);

        // ---- Layer 4 (result stays local: only this block's 16 needed) ----
        xs[t] = __hip_atomic_load(&xb3[t], __ATOMIC_ACQUIRE, __HIP_MEMORY_SCOPE_AGENT);
        __syncthreads();
        {
            float acc = 0.f;
            #pragma unroll
            for (int i = 0; i < 4; ++i) {
                float4 wv = *reinterpret_cast<const float4*>(W4 + (size_t)n * 256 + i * 64 + c * 4);
                float4 xv = *reinterpret_cast<const float4*>(xs + i * 64 + c * 4);
                acc += dot4(wv, xv);
            }
            #pragma unroll
            for (int off = 1; off <= 8; off <<= 1) acc += __shfl_xor(acc, off);
            if (c == 0) x4loc[q] = gelu_exact(acc + b4[n]);
        }
        __syncthreads();

        // ---- Layer 5 partial: block's 16 columns of W5 [12,256] ----
        if (t < 12) {
            float acc = 0.f;
            #pragma unroll
            for (int qq = 0; qq < 16; ++qq)
                acc += x4loc[qq] * W5[(size_t)t * 256 + m * 16 + qq];
            if (m == 0) acc += b5[t];
            atomicCAS((unsigned*)&w12[t], POISON, 0u);   // first toucher zeroes
            atomicAdd(&w12[t], acc);
        }
        __syncthreads();                                 // adds complete (vmcnt drained)
        if (t == 0) {
            atomicCAS(done, POISON, 0u);
            __threadfence();
            atomicAdd(done, 1u);
        }
    }

    // ---- Wait for w12 (read-only spin; POISON != 16, partials < 16) ----
    if (t == 0) {
        while (__hip_atomic_load(done, __ATOMIC_ACQUIRE,
                                 __HIP_MEMORY_SCOPE_AGENT) != NMLP)
            __builtin_amdgcn_s_sleep(8);
    }
    __syncthreads();
    if (t < 12)
        wl[t] = __hip_atomic_load(&w12[t], __ATOMIC_RELAXED, __HIP_MEMORY_SCOPE_AGENT);
    __syncthreads();

    // ---- Apply: pred[b,p,d] = sum_c feat[b,c,p] * w[c*3+d] ----
    float wr[12];
    #pragma unroll
    for (int i = 0; i < 12; ++i) wr[i] = wl[i];

    const int idx = m * 256 + t;               // 0..65535 quad index
    const int b   = idx >> 14;                 // batch
    const int pos = (idx & 16383) << 2;        // pixel start (x4)

    const float* fb = feat + (size_t)b * 4 * 65536 + pos;
    const float4 f0 = *reinterpret_cast<const float4*>(fb);
    const float4 f1 = *reinterpret_cast<const float4*>(fb + 65536);
    const float4 f2 = *reinterpret_cast<const float4*>(fb + 131072);
    const float4 f3 = *reinterpret_cast<const float4*>(fb + 196608);

    float r[12];
    #pragma unroll
    for (int dd = 0; dd < 3; ++dd) {
        r[0 + dd] = f0.x * wr[dd] + f1.x * wr[3 + dd] + f2.x * wr[6 + dd] + f3.x * wr[9 + dd];
        r[3 + dd] = f0.y * wr[dd] + f1.y * wr[3 + dd] + f2.y * wr[6 + dd] + f3.y * wr[9 + dd];
        r[6 + dd] = f0.z * wr[dd] + f1.z * wr[3 + dd] + f2.z * wr[6 + dd] + f3.z * wr[9 + dd];
        r[9 + dd] = f0.w * wr[dd] + f1.w * wr[3 + dd] + f2.w * wr[6 + dd] + f3.w * wr[9 + dd];
    }

    float* op = out + (size_t)(b * 65536 + pos) * 3;
    reinterpret_cast<float4*>(op)[0] = make_float4(r[0], r[1], r[2],  r[3]);
    reinterpret_cast<float4*>(op)[1] = make_float4(r[4], r[5], r[6],  r[7]);
    reinterpret_cast<float4*>(op)[2] = make_float4(r[8], r[9], r[10], r[11]);
}

extern "C" void kernel_launch(void* const* d_in, const int* in_sizes, int n_in,
                              void* d_out, int out_size, void* d_ws, size_t ws_size,
                              hipStream_t stream) {
    const float* feat = (const float*)d_in[0];
    const float* W1   = (const float*)d_in[1];
    const float* b1   = (const float*)d_in[2];
    const float* W2   = (const float*)d_in[3];
    const float* b2   = (const float*)d_in[4];
    const float* W3   = (const float*)d_in[5];
    const float* b3   = (const float*)d_in[6];
    const float* W4   = (const float*)d_in[7];
    const float* b4   = (const float*)d_in[8];
    const float* W5   = (const float*)d_in[9];
    const float* b5   = (const float*)d_in[10];

    float* out = (float*)d_out;   // [4, 65536, 3] fp32
    float* ws  = (float*)d_ws;

    fused3_kernel<<<256, 256, 0, stream>>>(W1, b1, W2, b2, W3, b3, W4, b4,
                                           W5, b5, feat, out, ws);
}

// Round 13
// 83.821 us; speedup vs baseline: 1.4754x; 1.4754x over previous
//
#include <hip/hip_runtime.h>

#define POISON 0xAAAAAAAAu
#define NMLP 16u

// Exact (non-approximate) GELU, matching jax.nn.gelu(approximate=False).
__device__ __forceinline__ float gelu_exact(float x) {
    return 0.5f * x * (1.0f + erff(x * 0.7071067811865475f));
}

__device__ __forceinline__ float dot4(float4 a, float4 b) {
    return a.x * b.x + a.y * b.y + a.z * b.z + a.w * b.w;
}

// Barrier among NMLP=16 blocks with NO acquire-load polling.
// r9/r12 lesson: __hip_atomic_load(ACQUIRE) spin loops emit a cache
// invalidate per poll; hundreds of spinners continuously invalidated L2 and
// the whole chip crawled at ~90 GB/s. Here polling is an atomic RMW
// (fetch_add of 0) which executes at the coherence point (always fresh, no
// broadcast invalidation), backed off with s_sleep(16) (~1024 cy). 16
// pollers on one line is negligible traffic. Slot starts as harness 0xAA
// poison; every participant CASes POISON->0 before arriving.
__device__ __forceinline__ void mlp_barrier(unsigned* slot) {
    __syncthreads();
    if (threadIdx.x == 0) {
        atomicCAS(slot, POISON, 0u);
        __threadfence();                      // data stores drained first
        atomicAdd(slot, 1u);
        while (__hip_atomic_fetch_add(slot, 0u, __ATOMIC_ACQUIRE,
                                      __HIP_MEMORY_SCOPE_AGENT) < NMLP)
            __builtin_amdgcn_s_sleep(16);
    }
    __syncthreads();
}

// K1: whole MLP on 16 blocks x 256 threads.
//  Layer layout (256x256): block m owns neurons m*16..m*16+15; 16 threads
//  per neuron (club c=0..15 reads 256B contiguous per i-step), 4-step
//  shfl_xor reduce within the club.
//  x2/x3 handoff: atomic-exchange stores (coherence-point RMW; immune to
//  stale-L2 issues) + plain loads after the acquire-RMW barrier.
//  L5 is LINEAR and apply is LINEAR in w12 => per-block partial w12 summed
//  with 12 fp32 atomicAdds; the K1->K2 kernel boundary is the final sync.
__global__ __launch_bounds__(256) void mlp16_kernel(
    const float* __restrict__ W1, const float* __restrict__ b1,
    const float* __restrict__ W2, const float* __restrict__ b2,
    const float* __restrict__ W3, const float* __restrict__ b3,
    const float* __restrict__ W4, const float* __restrict__ b4,
    const float* __restrict__ W5, const float* __restrict__ b5,
    float* __restrict__ ws)
{
    float*    w12  = ws;                     // 12 partial-sum accumulators
    unsigned* barA = (unsigned*)(ws + 32);
    unsigned* barB = (unsigned*)(ws + 64);
    float*    xb2  = ws + 128;               // 256 floats
    float*    xb3  = ws + 384;               // 256 floats

    __shared__ __align__(16) float xs[256];
    __shared__ float x4loc[16];

    const int t = threadIdx.x;
    const int m = blockIdx.x;                // 0..15
    const int q = t >> 4;                    // neuron-in-block 0..15
    const int c = t & 15;                    // club lane 0..15
    const int n = m * 16 + q;                // global neuron id

    // ---- Layer 1 (redundant per block; W1 is 4KB) ----
    {
        float4 w1r = *reinterpret_cast<const float4*>(W1 + t * 4);
        xs[t] = gelu_exact(w1r.z + w1r.w + b1[t]);
    }
    __syncthreads();

    // ---- Layer 2 ----
    {
        float acc = 0.f;
        #pragma unroll
        for (int i = 0; i < 4; ++i) {
            float4 wv = *reinterpret_cast<const float4*>(W2 + (size_t)n * 256 + i * 64 + c * 4);
            float4 xv = *reinterpret_cast<const float4*>(xs + i * 64 + c * 4);
            acc += dot4(wv, xv);
        }
        #pragma unroll
        for (int off = 1; off <= 8; off <<= 1) acc += __shfl_xor(acc, off);
        if (c == 0)
            __hip_atomic_exchange(&xb2[n], gelu_exact(acc + b2[n]),
                                  __ATOMIC_RELEASE, __HIP_MEMORY_SCOPE_AGENT);
    }
    mlp_barrier(barA);

    // ---- Layer 3 ----
    xs[t] = xb2[t];                          // fresh: post-acquire, poison-evicted
    __syncthreads();
    {
        float acc = 0.f;
        #pragma unroll
        for (int i = 0; i < 4; ++i) {
            float4 wv = *reinterpret_cast<const float4*>(W3 + (size_t)n * 256 + i * 64 + c * 4);
            float4 xv = *reinterpret_cast<const float4*>(xs + i * 64 + c * 4);
            acc += dot4(wv, xv);
        }
        #pragma unroll
        for (int off = 1; off <= 8; off <<= 1) acc += __shfl_xor(acc, off);
        if (c == 0)
            __hip_atomic_exchange(&xb3[n], gelu_exact(acc + b3[n]),
                                  __ATOMIC_RELEASE, __HIP_MEMORY_SCOPE_AGENT);
    }
    mlp_barrier(barB);

    // ---- Layer 4 (only this block's 16 outputs needed locally) ----
    xs[t] = xb3[t];
    __syncthreads();
    {
        float acc = 0.f;
        #pragma unroll
        for (int i = 0; i < 4; ++i) {
            float4 wv = *reinterpret_cast<const float4*>(W4 + (size_t)n * 256 + i * 64 + c * 4);
            float4 xv = *reinterpret_cast<const float4*>(xs + i * 64 + c * 4);
            acc += dot4(wv, xv);
        }
        #pragma unroll
        for (int off = 1; off <= 8; off <<= 1) acc += __shfl_xor(acc, off);
        if (c == 0) x4loc[q] = gelu_exact(acc + b4[n]);
    }
    __syncthreads();

    // ---- Layer 5 partial: w12_m[j] = sum_{qq} W5[j, m*16+qq] * x4loc[qq] ----
    if (t < 12) {
        float acc = 0.f;
        #pragma unroll
        for (int qq = 0; qq < 16; ++qq)
            acc += x4loc[qq] * W5[(size_t)t * 256 + m * 16 + qq];
        if (m == 0) acc += b5[t];
        atomicCAS((unsigned*)&w12[t], POISON, 0u);  // first toucher zeroes
        atomicAdd(&w12[t], acc);                    // visible to K2 via boundary
    }
}

// K2: pred[b,p,d] = sum_c feat[b,c,p] * w12[c*3+d].
// feat: [B=4, C=4, HW=65536] fp32, out: [B, HW, 3] fp32. 256 blk x 256 thr.
__global__ __launch_bounds__(256) void apply_kernel(
    const float* __restrict__ feat, const float* __restrict__ w12,
    float* __restrict__ out)
{
    __shared__ float wl[12];
    const int t = threadIdx.x;
    if (t < 12) wl[t] = w12[t];
    __syncthreads();

    float wr[12];
    #pragma unroll
    for (int i = 0; i < 12; ++i) wr[i] = wl[i];

    const int idx = blockIdx.x * 256 + t;            // 0..65535
    const int b   = idx >> 14;                        // batch
    const int pos = (idx & 16383) << 2;               // pixel start (x4)

    const float* fb = feat + (size_t)b * 4 * 65536 + pos;
    const float4 f0 = *reinterpret_cast<const float4*>(fb);
    const float4 f1 = *reinterpret_cast<const float4*>(fb + 65536);
    const float4 f2 = *reinterpret_cast<const float4*>(fb + 131072);
    const float4 f3 = *reinterpret_cast<const float4*>(fb + 196608);

    float r[12];
    #pragma unroll
    for (int dd = 0; dd < 3; ++dd) {
        r[0 + dd] = f0.x * wr[dd] + f1.x * wr[3 + dd] + f2.x * wr[6 + dd] + f3.x * wr[9 + dd];
        r[3 + dd] = f0.y * wr[dd] + f1.y * wr[3 + dd] + f2.y * wr[6 + dd] + f3.y * wr[9 + dd];
        r[6 + dd] = f0.z * wr[dd] + f1.z * wr[3 + dd] + f2.z * wr[6 + dd] + f3.z * wr[9 + dd];
        r[9 + dd] = f0.w * wr[dd] + f1.w * wr[3 + dd] + f2.w * wr[6 + dd] + f3.w * wr[9 + dd];
    }

    float* op = out + (size_t)(b * 65536 + pos) * 3;
    reinterpret_cast<float4*>(op)[0] = make_float4(r[0], r[1], r[2],  r[3]);
    reinterpret_cast<float4*>(op)[1] = make_float4(r[4], r[5], r[6],  r[7]);
    reinterpret_cast<float4*>(op)[2] = make_float4(r[8], r[9], r[10], r[11]);
}

extern "C" void kernel_launch(void* const* d_in, const int* in_sizes, int n_in,
                              void* d_out, int out_size, void* d_ws, size_t ws_size,
                              hipStream_t stream) {
    const float* feat = (const float*)d_in[0];
    const float* W1   = (const float*)d_in[1];
    const float* b1   = (const float*)d_in[2];
    const float* W2   = (const float*)d_in[3];
    const float* b2   = (const float*)d_in[4];
    const float* W3   = (const float*)d_in[5];
    const float* b3   = (const float*)d_in[6];
    const float* W4   = (const float*)d_in[7];
    const float* b4   = (const float*)d_in[8];
    const float* W5   = (const float*)d_in[9];
    const float* b5   = (const float*)d_in[10];

    float* out = (float*)d_out;   // [4, 65536, 3] fp32
    float* ws  = (float*)d_ws;

    mlp16_kernel<<<NMLP, 256, 0, stream>>>(W1, b1, W2, b2, W3, b3, W4, b4,
                                           W5, b5, ws);
    apply_kernel<<<256, 256, 0, stream>>>(feat, ws, out);
}